// Round 3
// baseline (404.049 us; speedup 1.0000x reference)
//
#include <hip/hip_runtime.h>
#include <hip/hip_bf16.h>

typedef unsigned short u16;
typedef short bf16x8 __attribute__((ext_vector_type(8)));
typedef float f32x4 __attribute__((ext_vector_type(4)));
typedef unsigned short u16x8 __attribute__((ext_vector_type(8)));
typedef unsigned short u16x4 __attribute__((ext_vector_type(4)));

__device__ __forceinline__ u16 f2bf(float f) {
    unsigned u = __float_as_uint(f);
    return (u16)((u + 0x7FFFu + ((u >> 16) & 1u)) >> 16);  // RNE, no NaNs here
}
__device__ __forceinline__ float bf2f(u16 h) {
    return __uint_as_float(((unsigned)h) << 16);
}

// ---------------------------------------------------------------------------
// Elementwise fp32 -> bf16 cast (x). n4 = elements/4.
// ---------------------------------------------------------------------------
__global__ __launch_bounds__(256) void cast_f32_bf16(const float4* __restrict__ src,
                                                     ushort4* __restrict__ dst, int n4) {
    int i = blockIdx.x * 256 + threadIdx.x;
    if (i < n4) {
        float4 v = src[i];
        ushort4 o;
        o.x = f2bf(v.x); o.y = f2bf(v.y); o.z = f2bf(v.z); o.w = f2bf(v.w);
        dst[i] = o;
    }
}

// ---------------------------------------------------------------------------
// 3x 1024x1024 fp32 -> bf16 transpose in one dispatch (z selects weight)
// ---------------------------------------------------------------------------
__global__ __launch_bounds__(256) void transpose_cast3(const float* __restrict__ W0,
                                                       const float* __restrict__ W1,
                                                       const float* __restrict__ W2,
                                                       u16* __restrict__ WT) {
    __shared__ float t[32][33];
    const float* W = (blockIdx.z == 0) ? W0 : (blockIdx.z == 1) ? W1 : W2;
    u16* Wt = WT + (long)blockIdx.z * 1048576;
    int bx = blockIdx.x * 32;  // n
    int by = blockIdx.y * 32;  // k
    int tx = threadIdx.x, ty = threadIdx.y;
    for (int r = ty; r < 32; r += 8)
        t[r][tx] = W[(by + r) * 1024 + bx + tx];
    __syncthreads();
    for (int r = ty; r < 32; r += 8)
        Wt[(long)(bx + r) * 1024 + by + tx] = f2bf(t[tx][r]);
}

// ---------------------------------------------------------------------------
// 256x256-tile bf16 MFMA GEMM, B^T input: C = A[M,K] * Bt[N,K]^T
// 512 threads = 8 waves (2M x 4N), each wave owns 128x64 of C as 8x4
// mfma_f32_16x16x32_bf16 fragments.
// Pipeline: BK=32, 4-deep LDS ring (4 x 32 KiB = 128 KiB), counted vmcnt(8)
// once per K-tile (tail 4/0) -- 3 tiles of loads always in flight.
// NEW: 2 phases per K-tile (16 MFMA each, m201 rhythm):
//   phase0: ds_read A[mf0-3]+B[nf0-3] (8xb128) || stage 2 A-GLLs of t+3
//           -> bar -> lgkm0 -> setprio1 -> 16 MFMA -> setprio0 -> bar
//   phase1: ds_read A[mf4-7] (B held in regs)  || stage 2 B-GLLs of t+3
//           -> bar -> lgkm0 -> setprio1 -> 16 MFMA -> setprio0
//           -> vmcnt(8) lgkm0 -> bar
// s_barrier syncs *issue*, so next phase's ds_reads run under the previous
// phase's draining MFMA pipe (LDS pipe || MFMA pipe overlap).
// LDS swizzle: slot = chunk ^ ((row>>1)&3), inverse-swizzled global source,
// linear global_load_lds dest, swizzled ds_read -> 0 bank conflicts (R2 PMC).
// MODE 0: fused QKV. cols<2048 -> bf16+bias into QK[16384][2048];
//         cols>=2048 -> bf16+bias TRANSPOSED into Vt[b][1024][2048].
// MODE 2: bf16 out * scale (scores). MODE 3: fp32 out (attn @ V).
// ---------------------------------------------------------------------------
#define GLL16(g, l)                                                     \
    __builtin_amdgcn_global_load_lds(                                   \
        (const __attribute__((address_space(1))) void*)(g),             \
        (__attribute__((address_space(3))) void*)(l), 16, 0, 0)

template <int MODE>
__global__ __launch_bounds__(512, 2)
void gemm_bt(const u16* __restrict__ A, int lda, long sA,
             const u16* __restrict__ Bt, int ldb, long sB,
             const float* __restrict__ bq_, const float* __restrict__ bk_,
             const float* __restrict__ bv_,
             void* __restrict__ Cout, void* __restrict__ Cout2,
             int ldc, long sC, int Kdim, float scale)
{
    // 4-stage ring: per stage A[256x32] bf16 (8192 u16) ++ B[256x32] (8192)
    __shared__ __align__(16) u16 lds[4 * 16384];

    const int tid  = threadIdx.x;
    const int wave = tid >> 6;
    const int lane = tid & 63;
    const int lrow = lane & 15;   // fragment row
    const int kc   = lane >> 4;   // fragment k-chunk (8 bf16 = 16 B)

    // XCD swizzle: flat%8 -> XCD; contiguous tile span per XCD (totals %8==0)
    const int gx = gridDim.x, gy = gridDim.y;
    int flat = (blockIdx.z * gy + blockIdx.y) * gx + blockIdx.x;
    int total = gx * gy * gridDim.z;
    int tile = (flat & 7) * (total >> 3) + (flat >> 3);
    const int bx = tile % gx;
    const int by = (tile / gx) % gy;
    const int bz = tile / (gx * gy);

    const u16* Ab = A + (long)bz * sA;
    const u16* Bb = Bt + (long)bz * sB;
    const int row0 = by * 256;
    const int col0 = bx * 256;
    const int wr = (wave & 1) * 128;   // 2 waves in M
    const int wc = (wave >> 1) * 64;   // 4 waves in N

    // staging: thread -> (row rS, linear slot tid&3) for rows rS and rS+128.
    // slot s holds global chunk c = s ^ ((r>>1)&3); (r+128>>1)&3 == (r>>1)&3.
    const int rS = tid >> 2;
    const int cS = (tid & 3) ^ ((tid >> 3) & 3);
    const u16* pa0 = Ab + (long)(row0 + rS) * lda + cS * 8;
    const u16* pa1 = pa0 + (long)128 * lda;
    const u16* pb0 = Bb + (long)(col0 + rS) * ldb + cS * 8;
    const u16* pb1 = pb0 + (long)128 * ldb;
    const int dA0 = tid * 8, dA1 = 4096 + tid * 8;
    const int dB0 = 8192 + tid * 8, dB1 = 12288 + tid * 8;

    // per-lane LDS fragment offsets (u16 units), swizzled
    int offA[8], offB[4];
#pragma unroll
    for (int mf = 0; mf < 8; ++mf) {
        int r = wr + mf * 16 + lrow;
        offA[mf] = r * 32 + (kc ^ ((r >> 1) & 3)) * 8;
    }
#pragma unroll
    for (int nf = 0; nf < 4; ++nf) {
        int r = wc + nf * 16 + lrow;
        offB[nf] = 8192 + r * 32 + (kc ^ ((r >> 1) & 3)) * 8;
    }

    f32x4 acc[8][4] = {};

    auto stageA = [&](int t) {
        u16* lb = &lds[(t & 3) * 16384];
        int ko = t * 32;
        GLL16(pa0 + ko, lb + dA0);
        GLL16(pa1 + ko, lb + dA1);
    };
    auto stageB = [&](int t) {
        u16* lb = &lds[(t & 3) * 16384];
        int ko = t * 32;
        GLL16(pb0 + ko, lb + dB0);
        GLL16(pb1 + ko, lb + dB1);
    };

    const int NT = Kdim >> 5;   // K-tiles of 32; all K here give NT >= 32
    stageA(0); stageB(0); stageA(1); stageB(1); stageA(2); stageB(2);
    asm volatile("s_waitcnt vmcnt(8)" ::: "memory");   // tile 0 landed (wave-local)
    __builtin_amdgcn_s_barrier();                      // published block-wide

    for (int t = 0; t < NT; ++t) {
        const u16* lb = &lds[(t & 3) * 16384];
        bf16x8 af[4], bfr[4];

        // ---------------- phase 0: quadrant mf0-3 x nf0-3 ----------------
#pragma unroll
        for (int i = 0; i < 4; ++i) {
            af[i]  = *(const bf16x8*)&lb[offA[i]];
            bfr[i] = *(const bf16x8*)&lb[offB[i]];
        }
        if (t + 3 < NT) stageA(t + 3);
        __builtin_amdgcn_s_barrier();
        asm volatile("s_waitcnt lgkmcnt(0)" ::: "memory");
        __builtin_amdgcn_s_setprio(1);
#pragma unroll
        for (int mf = 0; mf < 4; ++mf)
#pragma unroll
            for (int nf = 0; nf < 4; ++nf)
                acc[mf][nf] = __builtin_amdgcn_mfma_f32_16x16x32_bf16(
                    af[mf], bfr[nf], acc[mf][nf], 0, 0, 0);
        __builtin_amdgcn_s_setprio(0);
        __builtin_amdgcn_s_barrier();

        // ---------------- phase 1: quadrant mf4-7 x nf0-3 ----------------
#pragma unroll
        for (int i = 0; i < 4; ++i)
            af[i] = *(const bf16x8*)&lb[offA[4 + i]];
        if (t + 3 < NT) stageB(t + 3);
        __builtin_amdgcn_s_barrier();
        asm volatile("s_waitcnt lgkmcnt(0)" ::: "memory");
        __builtin_amdgcn_s_setprio(1);
#pragma unroll
        for (int mf = 0; mf < 4; ++mf)
#pragma unroll
            for (int nf = 0; nf < 4; ++nf)
                acc[4 + mf][nf] = __builtin_amdgcn_mfma_f32_16x16x32_bf16(
                    af[mf], bfr[nf], acc[4 + mf][nf], 0, 0, 0);
        __builtin_amdgcn_s_setprio(0);

        // end-of-tile: counted wait for next tile's data, then publish
        if (t < NT - 3) {
            asm volatile("s_waitcnt vmcnt(8) lgkmcnt(0)" ::: "memory");
            __builtin_amdgcn_s_barrier();
        } else if (t == NT - 3) {
            asm volatile("s_waitcnt vmcnt(4) lgkmcnt(0)" ::: "memory");
            __builtin_amdgcn_s_barrier();
        } else if (t == NT - 2) {
            asm volatile("s_waitcnt vmcnt(0) lgkmcnt(0)" ::: "memory");
            __builtin_amdgcn_s_barrier();
        }
        // t == NT-1: fall through to epilogue (acc in regs)
    }

    // epilogue: 16x16 C/D layout col = lane&15, row = (lane>>4)*4 + reg
    const int lq = kc;  // lane>>4
    if (MODE == 0) {
        if (col0 < 2048) {
            const float* bp = (col0 < 1024) ? bq_ : bk_;
#pragma unroll
            for (int mf = 0; mf < 8; ++mf) {
#pragma unroll
                for (int nf = 0; nf < 4; ++nf) {
                    int col = col0 + wc + nf * 16 + lrow;
                    float badd = bp[col & 1023];
                    int rbase = row0 + wr + mf * 16 + lq * 4;
#pragma unroll
                    for (int g = 0; g < 4; ++g)
                        ((u16*)Cout)[(long)(rbase + g) * 2048 + col] =
                            f2bf(acc[mf][nf][g] + badd);
                }
            }
        } else {
            // V part: store transposed into Vt[b][1024][2048], 4 rows packed
#pragma unroll
            for (int mf = 0; mf < 8; ++mf) {
#pragma unroll
                for (int nf = 0; nf < 4; ++nf) {
                    int d = col0 + wc + nf * 16 + lrow - 2048;
                    float badd = bv_[d];
                    int rbase = row0 + wr + mf * 16 + lq * 4;
                    int b = rbase >> 11, m = rbase & 2047;
                    u16x4 pk;
#pragma unroll
                    for (int g = 0; g < 4; ++g) pk[g] = f2bf(acc[mf][nf][g] + badd);
                    *(u16x4*)((u16*)Cout2 + ((long)b << 21) + ((long)d << 11) + m) = pk;
                }
            }
        }
    } else {
#pragma unroll
        for (int mf = 0; mf < 8; ++mf) {
#pragma unroll
            for (int nf = 0; nf < 4; ++nf) {
                int col = col0 + wc + nf * 16 + lrow;
                int rbase = row0 + wr + mf * 16 + lq * 4;
#pragma unroll
                for (int g = 0; g < 4; ++g) {
                    long idx = (long)bz * sC + (long)(rbase + g) * ldc + col;
                    if (MODE == 2)
                        ((u16*)Cout)[idx] = f2bf(acc[mf][nf][g] * scale);
                    else
                        ((float*)Cout)[idx] = acc[mf][nf][g];
                }
            }
        }
    }
}

// ---------------------------------------------------------------------------
// In-place row softmax over bf16 [16384 rows][2048], one block per row.
// ---------------------------------------------------------------------------
__global__ __launch_bounds__(256) void softmax_rows(u16* __restrict__ S) {
    __shared__ float red[4];
    const long row = blockIdx.x;
    u16* p = S + row * 2048;
    const int tid = threadIdx.x;
    const int lane = tid & 63, wv = tid >> 6;

    u16x8 raw = *(const u16x8*)(p + tid * 8);
    float v[8];
#pragma unroll
    for (int i = 0; i < 8; ++i) v[i] = bf2f(raw[i]);

    float m = -1e30f;
#pragma unroll
    for (int i = 0; i < 8; ++i) m = fmaxf(m, v[i]);
    for (int off = 32; off > 0; off >>= 1) m = fmaxf(m, __shfl_down(m, off));
    if (lane == 0) red[wv] = m;
    __syncthreads();
    m = fmaxf(fmaxf(red[0], red[1]), fmaxf(red[2], red[3]));

    float s = 0.0f;
#pragma unroll
    for (int i = 0; i < 8; ++i) { v[i] = __expf(v[i] - m); s += v[i]; }
    for (int off = 32; off > 0; off >>= 1) s += __shfl_down(s, off);
    __syncthreads();
    if (lane == 0) red[wv] = s;
    __syncthreads();
    s = red[0] + red[1] + red[2] + red[3];
    float inv = 1.0f / s;

    u16x8 o;
#pragma unroll
    for (int i = 0; i < 8; ++i) o[i] = f2bf(v[i] * inv);
    *(u16x8*)(p + tid * 8) = o;
}

// ---------------------------------------------------------------------------
extern "C" void kernel_launch(void* const* d_in, const int* in_sizes, int n_in,
                              void* d_out, int out_size, void* d_ws, size_t ws_size,
                              hipStream_t stream) {
    const float* x  = (const float*)d_in[0];
    const float* Wq = (const float*)d_in[1];
    const float* bq = (const float*)d_in[2];
    const float* Wk = (const float*)d_in[3];
    const float* bk = (const float*)d_in[4];
    const float* Wv = (const float*)d_in[5];
    const float* bv = (const float*)d_in[6];
    float* out = (float*)d_out;

    // workspace layout (bytes)
    char* ws = (char*)d_ws;
    u16* xb = (u16*)(ws);                        // 16384x1024 bf16   = 32 MiB
    u16* WT = (u16*)(ws + 33554432);             // 3072x1024 bf16    =  6 MiB
    u16* QK = (u16*)(ws + 39845888);             // 16384x2048 bf16   = 64 MiB
    u16* Vt = (u16*)(ws + 106954752);            // 8 x 1024x2048 bf16= 32 MiB
    u16* S  = (u16*)(ws + 140509184);            // 8 x 2048x2048 bf16= 64 MiB
    // total 207,618,048 bytes

    // 1) casts
    cast_f32_bf16<<<16384, 256, 0, stream>>>((const float4*)x, (ushort4*)xb, 4194304);
    dim3 tg(32, 32, 3), tb(32, 8);
    transpose_cast3<<<tg, tb, 0, stream>>>(Wq, Wk, Wv, WT);

    // 2) fused QKV projection: [16384,3072] = xb @ WT^T + b   (768 blocks = 3 CU-rounds)
    dim3 gp(12, 64, 1);
    gemm_bt<0><<<gp, 512, 0, stream>>>(xb, 1024, 0, WT, 1024, 0,
                                       bq, bk, bv, QK, Vt, 0, 0, 1024, 1.0f);

    // 3) scores S[b] = (Q[b] @ K[b]^T) / 32, bf16   (512 blocks = 2 rounds)
    dim3 gs(8, 8, 8);
    gemm_bt<2><<<gs, 512, 0, stream>>>(QK, 2048, 2048L * 2048, QK + 1024, 2048, 2048L * 2048,
                                       nullptr, nullptr, nullptr, S, nullptr,
                                       2048, 2048L * 2048, 1024, 0.03125f);

    // 4) row softmax in place
    softmax_rows<<<16384, 256, 0, stream>>>(S);

    // 5) out[b] = P[b] @ V[b]   (via Vt, fp32 out; 256 blocks = 1 round)
    dim3 gv(4, 8, 8);
    gemm_bt<3><<<gv, 512, 0, stream>>>(S, 2048, 2048L * 2048, Vt, 2048, 1024L * 2048,
                                       nullptr, nullptr, nullptr, out, nullptr,
                                       1024, 2048L * 1024, 2048, 1.0f);
}

// Round 4
// 367.259 us; speedup vs baseline: 1.1002x; 1.1002x over previous
//
#include <hip/hip_runtime.h>
#include <hip/hip_bf16.h>

typedef unsigned short u16;
typedef short bf16x8 __attribute__((ext_vector_type(8)));
typedef float f32x4 __attribute__((ext_vector_type(4)));
typedef unsigned short u16x8 __attribute__((ext_vector_type(8)));
typedef unsigned short u16x4 __attribute__((ext_vector_type(4)));

__device__ __forceinline__ u16 f2bf(float f) {
    unsigned u = __float_as_uint(f);
    return (u16)((u + 0x7FFFu + ((u >> 16) & 1u)) >> 16);  // RNE, no NaNs here
}
__device__ __forceinline__ float bf2f(u16 h) {
    return __uint_as_float(((unsigned)h) << 16);
}

// ---------------------------------------------------------------------------
// Elementwise fp32 -> bf16 cast (x). n4 = elements/4.
// ---------------------------------------------------------------------------
__global__ __launch_bounds__(256) void cast_f32_bf16(const float4* __restrict__ src,
                                                     ushort4* __restrict__ dst, int n4) {
    int i = blockIdx.x * 256 + threadIdx.x;
    if (i < n4) {
        float4 v = src[i];
        ushort4 o;
        o.x = f2bf(v.x); o.y = f2bf(v.y); o.z = f2bf(v.z); o.w = f2bf(v.w);
        dst[i] = o;
    }
}

// ---------------------------------------------------------------------------
// 3x 1024x1024 fp32 -> bf16 transpose in one dispatch (z selects weight)
// ---------------------------------------------------------------------------
__global__ __launch_bounds__(256) void transpose_cast3(const float* __restrict__ W0,
                                                       const float* __restrict__ W1,
                                                       const float* __restrict__ W2,
                                                       u16* __restrict__ WT) {
    __shared__ float t[32][33];
    const float* W = (blockIdx.z == 0) ? W0 : (blockIdx.z == 1) ? W1 : W2;
    u16* Wt = WT + (long)blockIdx.z * 1048576;
    int bx = blockIdx.x * 32;  // n
    int by = blockIdx.y * 32;  // k
    int tx = threadIdx.x, ty = threadIdx.y;
    for (int r = ty; r < 32; r += 8)
        t[r][tx] = W[(by + r) * 1024 + bx + tx];
    __syncthreads();
    for (int r = ty; r < 32; r += 8)
        Wt[(long)(bx + r) * 1024 + by + tx] = f2bf(t[tx][r]);
}

// ---------------------------------------------------------------------------
// 256x256-tile bf16 MFMA GEMM, B^T input: C = A[M,K] * Bt[N,K]^T
// 512 threads = 8 waves (2M x 4N); per wave 128x64 of C = 8mf x 4nf
// mfma_f32_16x16x32_bf16 fragments.
//
// m201-style schedule: BK=64, 2-buffer LDS dbuf (2 x 64 KiB = 128 KiB),
// 4 phases per K-tile, each = one C-quadrant (16 MFMA):
//   ph0: acc[0-3][0-1]  reads A-lo(8) + B-lo(4)
//   ph1: acc[0-3][2-3]  reads B-hi(4)          (A-lo held in regs)
//   ph2: acc[4-7][0-1]  reads A-hi(8)          (B-lo held)
//   ph3: acc[4-7][2-3]  no reads               (A-hi, B-hi held)
// Staging: 4 groups per tile (2 GLL each), CONSUMPTION-ORDERED: LDS rows are
// permuted so group g is exactly phase g's consumption set:
//   G0 = A rows for mf0-3 (all waves), G1 = B rows nf0-1, G2 = B rows nf2-3,
//   G3 = A rows mf4-7.
// Phase p of tile t stages G_p(t+1); uniform s_waitcnt vmcnt(6) + s_barrier
// per phase guarantees exactly G_p(t) landed (3 groups = 6 loads in flight,
// never drains). Last tile peels vmcnt(4)/(2)/(0).
// ds_reads AFTER the barrier; compiler inserts fine-grained lgkmcnt.
// Swizzle: LDS cell (l, s) holds global (r = perm^-1(l), chunk = s ^ (l&7));
// l&7 == r&7 always, so fragment reads spread 16 lanes over 8 slots (2/slot,
// free) -> 0 bank conflicts (verified R2 PMC with same involution scheme).
//
// MODE 0: fused QKV. cols<2048 -> bf16+bias into QK[16384][2048];
//         cols>=2048 -> bf16+bias TRANSPOSED into Vt[b][1024][2048].
// MODE 2: bf16 out * scale (scores). MODE 3: fp32 out (attn @ V).
// ---------------------------------------------------------------------------
#define GLL16(g, l)                                                     \
    __builtin_amdgcn_global_load_lds(                                   \
        (const __attribute__((address_space(1))) void*)(g),             \
        (__attribute__((address_space(3))) void*)(l), 16, 0, 0)

#define VMB(n)                                                          \
    do {                                                                \
        asm volatile("s_waitcnt vmcnt(" #n ")" ::: "memory");           \
        __builtin_amdgcn_s_barrier();                                   \
    } while (0)

template <int MODE>
__global__ __launch_bounds__(512, 2)
void gemm_bt(const u16* __restrict__ A, int lda, long sA,
             const u16* __restrict__ Bt, int ldb, long sB,
             const float* __restrict__ bq_, const float* __restrict__ bk_,
             const float* __restrict__ bv_,
             void* __restrict__ Cout, void* __restrict__ Cout2,
             int ldc, long sC, int Kdim, float scale)
{
    // dbuf: per buffer A[256 rows][64 K] (16384 u16) ++ B same -> 32768 u16
    __shared__ __align__(16) u16 lds[2 * 32768];

    const int tid  = threadIdx.x;
    const int wave = tid >> 6;
    const int lane = tid & 63;
    const int lrow = lane & 15;   // fragment row within 16
    const int hi   = lane >> 4;   // fragment k-chunk quarter

    // XCD swizzle: flat%8 -> XCD; contiguous tile span per XCD (totals %8==0)
    const int gx = gridDim.x, gy = gridDim.y;
    int flat = (blockIdx.z * gy + blockIdx.y) * gx + blockIdx.x;
    int total = gx * gy * gridDim.z;
    int tile = (flat & 7) * (total >> 3) + (flat >> 3);
    const int bx = tile % gx;
    const int by = (tile / gx) % gy;
    const int bz = tile / (gx * gy);

    const u16* Ab = A + (long)bz * sA;
    const u16* Bb = Bt + (long)bz * sB;
    const int row0 = by * 256;
    const int col0 = bx * 256;
    const int wr = (wave & 1) * 128;   // 2 waves in M
    const int wc = (wave >> 1) * 64;   // 4 waves in N

    // ---- staging thread-constants -------------------------------------
    // GLL j covers LDS perm-rows l = j*64 + (tid>>3), slot s = tid&7.
    // chunk c = s ^ (l&7) (same for j=0,1 since l&7 == (tid>>3)&7).
    const int t3 = tid >> 3, s7 = tid & 7;
    const int cS = s7 ^ (t3 & 7);
    // A perm: quarter order [q0,q2 | q1,q3]. G0 rows: j0 -> t3, j1 -> 128+t3.
    // G3 = G0 + 64 rows.
    const u16* pa = Ab + (long)(row0 + t3) * lda + cS * 8;
    // B perm: l in [0,128) -> r = (l>>5)*64 + (l&31); G2 = G1 + 32 rows.
    const int rB0 = ((t3 >> 5) << 6) + (t3 & 31);          // j0
    const int rB1 = (((t3 >> 5) + 2) << 6) + (t3 & 31);    // j1 (l = 64+t3)
    const u16* pb0 = Bb + (long)(col0 + rB0) * ldb + cS * 8;
    const u16* pb1 = Bb + (long)(col0 + rB1) * ldb + cS * 8;
    const long a64 = (long)64 * lda, a128 = (long)128 * lda;
    const long b32 = (long)32 * ldb;
    const int dj0 = tid * 8, dj1 = 4096 + tid * 8;   // u16 offsets

#define STAGE_G(t, g)                                                       \
    do {                                                                    \
        u16* buf_ = &lds[((t) & 1) * 32768];                                \
        const long ko_ = (long)(t) * 64;                                    \
        if ((g) == 0) {                                                     \
            GLL16(pa + ko_, buf_ + dj0);                                    \
            GLL16(pa + a128 + ko_, buf_ + dj1);                             \
        } else if ((g) == 1) {                                              \
            GLL16(pb0 + ko_, buf_ + 16384 + dj0);                           \
            GLL16(pb1 + ko_, buf_ + 16384 + dj1);                           \
        } else if ((g) == 2) {                                              \
            GLL16(pb0 + b32 + ko_, buf_ + 24576 + dj0);                     \
            GLL16(pb1 + b32 + ko_, buf_ + 24576 + dj1);                     \
        } else {                                                            \
            GLL16(pa + a64 + ko_, buf_ + 8192 + dj0);                       \
            GLL16(pa + a64 + a128 + ko_, buf_ + 8192 + dj1);                \
        }                                                                   \
    } while (0)

    // ---- fragment LDS offsets (u16), swizzled -------------------------
    // off = permrow*64 + slot*8; slot(kk,hi) = (kk*4+hi) ^ (r&7); r&7 = lrow&7
    // kk=1 flips bit2 of slot -> off ^ 32.
    const int sl8 = (hi ^ (lrow & 7)) * 8;
    const int azb = ((wave & 1) << 12) + lrow * 64 + sl8;           // A base
    const int bzb = 16384 + ((wave >> 1) << 11) + lrow * 64 + sl8;  // B base
    // offA(mf) = azb + (mf&3)*1024 + (mf>>2)*8192
    // offB(nf) = bzb + {0,1024,8192,9216}[nf]

    f32x4 acc[8][4] = {};
    bf16x8 af[4][2], bl[2][2], bh[2][2];

#define LOAD_A(lb, half)                                                    \
    _Pragma("unroll") for (int m = 0; m < 4; ++m)                           \
    _Pragma("unroll") for (int k = 0; k < 2; ++k)                           \
        af[m][k] = *(const bf16x8*)&(lb)[(azb + m * 1024 + (half) * 8192) ^ (k * 32)];

#define LOAD_BL(lb)                                                         \
    _Pragma("unroll") for (int n = 0; n < 2; ++n)                           \
    _Pragma("unroll") for (int k = 0; k < 2; ++k)                           \
        bl[n][k] = *(const bf16x8*)&(lb)[(bzb + n * 1024) ^ (k * 32)];

#define LOAD_BH(lb)                                                         \
    _Pragma("unroll") for (int n = 0; n < 2; ++n)                           \
    _Pragma("unroll") for (int k = 0; k < 2; ++k)                           \
        bh[n][k] = *(const bf16x8*)&(lb)[(bzb + 8192 + n * 1024) ^ (k * 32)];

#define MMA_Q(barr, mb, nb)                                                 \
    do {                                                                    \
        __builtin_amdgcn_s_setprio(1);                                      \
        _Pragma("unroll") for (int k = 0; k < 2; ++k)                       \
        _Pragma("unroll") for (int m = 0; m < 4; ++m)                       \
        _Pragma("unroll") for (int n = 0; n < 2; ++n)                       \
            acc[(mb) + m][(nb) + n] = __builtin_amdgcn_mfma_f32_16x16x32_bf16( \
                af[m][k], barr[n][k], acc[(mb) + m][(nb) + n], 0, 0, 0);    \
        __builtin_amdgcn_s_setprio(0);                                      \
    } while (0)

    const int NT = Kdim >> 6;   // K-tiles of 64 (NT >= 16 here)
    STAGE_G(0, 0); STAGE_G(0, 1); STAGE_G(0, 2); STAGE_G(0, 3);

    for (int t = 0; t < NT - 1; ++t) {
        const u16* lb = &lds[(t & 1) * 32768];
        STAGE_G(t + 1, 0);
        VMB(6);                       // guarantees G0(t), G1(t)
        LOAD_A(lb, 0); LOAD_BL(lb);
        MMA_Q(bl, 0, 0);
        STAGE_G(t + 1, 1);
        VMB(6);                       // guarantees G2(t)
        LOAD_BH(lb);
        MMA_Q(bh, 0, 2);
        STAGE_G(t + 1, 2);
        VMB(6);                       // guarantees G3(t)
        LOAD_A(lb, 1);
        MMA_Q(bl, 4, 0);
        STAGE_G(t + 1, 3);
        VMB(6);
        MMA_Q(bh, 4, 2);
    }
    {   // last tile: peel with tightening counts, no staging
        const u16* lb = &lds[((NT - 1) & 1) * 32768];
        VMB(4);
        LOAD_A(lb, 0); LOAD_BL(lb);
        MMA_Q(bl, 0, 0);
        VMB(2);
        LOAD_BH(lb);
        MMA_Q(bh, 0, 2);
        VMB(0);
        LOAD_A(lb, 1);
        MMA_Q(bl, 4, 0);
        MMA_Q(bh, 4, 2);
    }

    // epilogue: 16x16 C/D layout col = lane&15, row = (lane>>4)*4 + reg
    const int lq = hi;
    if (MODE == 0) {
        if (col0 < 2048) {
            const float* bp = (col0 < 1024) ? bq_ : bk_;
#pragma unroll
            for (int mf = 0; mf < 8; ++mf) {
#pragma unroll
                for (int nf = 0; nf < 4; ++nf) {
                    int col = col0 + wc + nf * 16 + lrow;
                    float badd = bp[col & 1023];
                    int rbase = row0 + wr + mf * 16 + lq * 4;
#pragma unroll
                    for (int g = 0; g < 4; ++g)
                        ((u16*)Cout)[(long)(rbase + g) * 2048 + col] =
                            f2bf(acc[mf][nf][g] + badd);
                }
            }
        } else {
            // V part: store transposed into Vt[b][1024][2048], 4 rows packed
#pragma unroll
            for (int mf = 0; mf < 8; ++mf) {
#pragma unroll
                for (int nf = 0; nf < 4; ++nf) {
                    int d = col0 + wc + nf * 16 + lrow - 2048;
                    float badd = bv_[d];
                    int rbase = row0 + wr + mf * 16 + lq * 4;
                    int b = rbase >> 11, m = rbase & 2047;
                    u16x4 pk;
#pragma unroll
                    for (int g = 0; g < 4; ++g) pk[g] = f2bf(acc[mf][nf][g] + badd);
                    *(u16x4*)((u16*)Cout2 + ((long)b << 21) + ((long)d << 11) + m) = pk;
                }
            }
        }
    } else {
#pragma unroll
        for (int mf = 0; mf < 8; ++mf) {
#pragma unroll
            for (int nf = 0; nf < 4; ++nf) {
                int col = col0 + wc + nf * 16 + lrow;
                int rbase = row0 + wr + mf * 16 + lq * 4;
#pragma unroll
                for (int g = 0; g < 4; ++g) {
                    long idx = (long)bz * sC + (long)(rbase + g) * ldc + col;
                    if (MODE == 2)
                        ((u16*)Cout)[idx] = f2bf(acc[mf][nf][g] * scale);
                    else
                        ((float*)Cout)[idx] = acc[mf][nf][g];
                }
            }
        }
    }
}

// ---------------------------------------------------------------------------
// In-place row softmax over bf16 [16384 rows][2048], one block per row.
// ---------------------------------------------------------------------------
__global__ __launch_bounds__(256) void softmax_rows(u16* __restrict__ S) {
    __shared__ float red[4];
    const long row = blockIdx.x;
    u16* p = S + row * 2048;
    const int tid = threadIdx.x;
    const int lane = tid & 63, wv = tid >> 6;

    u16x8 raw = *(const u16x8*)(p + tid * 8);
    float v[8];
#pragma unroll
    for (int i = 0; i < 8; ++i) v[i] = bf2f(raw[i]);

    float m = -1e30f;
#pragma unroll
    for (int i = 0; i < 8; ++i) m = fmaxf(m, v[i]);
    for (int off = 32; off > 0; off >>= 1) m = fmaxf(m, __shfl_down(m, off));
    if (lane == 0) red[wv] = m;
    __syncthreads();
    m = fmaxf(fmaxf(red[0], red[1]), fmaxf(red[2], red[3]));

    float s = 0.0f;
#pragma unroll
    for (int i = 0; i < 8; ++i) { v[i] = __expf(v[i] - m); s += v[i]; }
    for (int off = 32; off > 0; off >>= 1) s += __shfl_down(s, off);
    __syncthreads();
    if (lane == 0) red[wv] = s;
    __syncthreads();
    s = red[0] + red[1] + red[2] + red[3];
    float inv = 1.0f / s;

    u16x8 o;
#pragma unroll
    for (int i = 0; i < 8; ++i) o[i] = f2bf(v[i] * inv);
    *(u16x8*)(p + tid * 8) = o;
}

// ---------------------------------------------------------------------------
extern "C" void kernel_launch(void* const* d_in, const int* in_sizes, int n_in,
                              void* d_out, int out_size, void* d_ws, size_t ws_size,
                              hipStream_t stream) {
    const float* x  = (const float*)d_in[0];
    const float* Wq = (const float*)d_in[1];
    const float* bq = (const float*)d_in[2];
    const float* Wk = (const float*)d_in[3];
    const float* bk = (const float*)d_in[4];
    const float* Wv = (const float*)d_in[5];
    const float* bv = (const float*)d_in[6];
    float* out = (float*)d_out;

    // workspace layout (bytes)
    char* ws = (char*)d_ws;
    u16* xb = (u16*)(ws);                        // 16384x1024 bf16   = 32 MiB
    u16* WT = (u16*)(ws + 33554432);             // 3072x1024 bf16    =  6 MiB
    u16* QK = (u16*)(ws + 39845888);             // 16384x2048 bf16   = 64 MiB
    u16* Vt = (u16*)(ws + 106954752);            // 8 x 1024x2048 bf16= 32 MiB
    u16* S  = (u16*)(ws + 140509184);            // 8 x 2048x2048 bf16= 64 MiB
    // total 207,618,048 bytes

    // 1) casts
    cast_f32_bf16<<<16384, 256, 0, stream>>>((const float4*)x, (ushort4*)xb, 4194304);
    dim3 tg(32, 32, 3), tb(32, 8);
    transpose_cast3<<<tg, tb, 0, stream>>>(Wq, Wk, Wv, WT);

    // 2) fused QKV projection: [16384,3072] = xb @ WT^T + b   (768 blocks)
    dim3 gp(12, 64, 1);
    gemm_bt<0><<<gp, 512, 0, stream>>>(xb, 1024, 0, WT, 1024, 0,
                                       bq, bk, bv, QK, Vt, 0, 0, 1024, 1.0f);

    // 3) scores S[b] = (Q[b] @ K[b]^T) / 32, bf16   (512 blocks)
    dim3 gs(8, 8, 8);
    gemm_bt<2><<<gs, 512, 0, stream>>>(QK, 2048, 2048L * 2048, QK + 1024, 2048, 2048L * 2048,
                                       nullptr, nullptr, nullptr, S, nullptr,
                                       2048, 2048L * 2048, 1024, 0.03125f);

    // 4) row softmax in place
    softmax_rows<<<16384, 256, 0, stream>>>(S);

    // 5) out[b] = P[b] @ V[b]   (via Vt, fp32 out; 256 blocks)
    dim3 gv(4, 8, 8);
    gemm_bt<3><<<gv, 512, 0, stream>>>(S, 2048, 2048L * 2048, Vt, 2048, 1024L * 2048,
                                       nullptr, nullptr, nullptr, out, nullptr,
                                       1024, 2048L * 1024, 2048, 1.0f);
}